// Round 9
// baseline (141.535 us; speedup 1.0000x reference)
//
#include <hip/hip_runtime.h>
#include <hip/hip_bf16.h>
#include <stdint.h>

#define NTOK 2048
#define HDIM 1024
#define NEXP 16
#define TOPK 4
#define IR   512
#define ISH  1024
#define RSCALE 2.5f

typedef short bf16x4 __attribute__((ext_vector_type(4)));
typedef short bf16x8 __attribute__((ext_vector_type(8)));
typedef float f32x4  __attribute__((ext_vector_type(4)));

static __device__ __forceinline__ unsigned short f2bf(float f){
  union { float fv; uint32_t u; } v; v.fv = f;
  uint32_t r = v.u + 0x7fffu + ((v.u >> 16) & 1u);
  return (unsigned short)(r >> 16);
}
static __device__ __forceinline__ float bf2f(unsigned short s){
  union { uint32_t u; float f; } v; v.u = ((uint32_t)s) << 16;
  return v.f;
}

static __device__ __forceinline__ void gl_lds16(const void* gp, void* lp){
  __builtin_amdgcn_global_load_lds(
      (const __attribute__((address_space(1))) unsigned int*)gp,
      (__attribute__((address_space(3))) unsigned int*)lp, 16, 0, 0);
}

// ---------------- router: logits, sigmoid, top-4, x->bf16 ----------------
__global__ __launch_bounds__(256) void router_kernel(
    const float* __restrict__ x, const float* __restrict__ gw,
    float* __restrict__ topkw, int* __restrict__ choice,
    unsigned short* __restrict__ xbf)
{
  __shared__ float sgw[NEXP][HDIM + 8];
  const int tid = threadIdx.x;
  for (int f = tid; f < HDIM * NEXP; f += 256){
    int i = f >> 4, e = f & 15;
    sgw[e][i] = gw[f];
  }
  __syncthreads();
  const int lane = tid & 63;
  const int t = blockIdx.x * 4 + (tid >> 6);

  float s[NEXP];
  #pragma unroll
  for (int e = 0; e < NEXP; e++) s[e] = 0.f;
  #pragma unroll
  for (int j = 0; j < 8; j++){
    const int off = 128 * j + lane * 2;
    float2 xv = *(const float2*)(x + (size_t)t * HDIM + off);
    ushort2 xs = { f2bf(xv.x), f2bf(xv.y) };
    *(ushort2*)(xbf + (size_t)t * HDIM + off) = xs;
    #pragma unroll
    for (int e = 0; e < NEXP; e++){
      float2 gv = *(const float2*)(&sgw[e][off]);
      s[e] += xv.x * gv.x + xv.y * gv.y;
    }
  }
  #pragma unroll
  for (int e = 0; e < NEXP; e++){
    #pragma unroll
    for (int off = 32; off; off >>= 1)
      s[e] += __shfl_xor(s[e], off);
  }
  float sc[NEXP];
  #pragma unroll
  for (int e = 0; e < NEXP; e++) sc[e] = 1.f / (1.f + __expf(-s[e]));

  unsigned mask = 0; float w[TOPK]; int id[TOPK];
  #pragma unroll
  for (int k = 0; k < TOPK; k++){
    float best = -1e30f; int bi = 0;
    #pragma unroll
    for (int e = 0; e < NEXP; e++){
      if (!((mask >> e) & 1u) && sc[e] > best){ best = sc[e]; bi = e; }
    }
    mask |= 1u << bi; id[k] = bi; w[k] = best;
  }
  float inv = 1.f / (w[0] + w[1] + w[2] + w[3]);
  if (lane == 0){
    #pragma unroll
    for (int k = 0; k < TOPK; k++){
      topkw[t * TOPK + k] = w[k] * inv;
      choice[t * TOPK + k] = id[k];
    }
  }
}

// ---------------- build per-expert lists deterministically ----------------
__global__ __launch_bounds__(256) void build_lists(
    const int* __restrict__ choice, int* __restrict__ counts, int* __restrict__ lists)
{
  const int e = blockIdx.x;
  const int tid = threadIdx.x;
  __shared__ int scnt[256];
  const int base = tid * 32;
  unsigned m = 0; int local = 0;
  #pragma unroll
  for (int i = 0; i < 32; i++){
    bool hit = (choice[base + i] == e);
    m |= (unsigned)hit << i;
    local += hit;
  }
  scnt[tid] = local;
  __syncthreads();
  int v = local;
  for (int off = 1; off < 256; off <<= 1){
    int add = (tid >= off) ? scnt[tid - off] : 0;
    __syncthreads();
    v += add; scnt[tid] = v;
    __syncthreads();
  }
  int pos = v - local;
  #pragma unroll
  for (int i = 0; i < 32; i++){
    if ((m >> i) & 1u) lists[e * NTOK + pos++] = base + i;
  }
  if (tid == 255) counts[e] = v;
}

// ---------------- fused gate_up GEMM (fp32 B direct, convert+transpose in staging) ----------------
// Grid 768. L<512 routed: e=L>>5, r=L&31: n-panel p=r&7 (XCD-pinned), mIdx=r>>3, NCH=4.
// L>=512 shared: v=L-512: p=v&15, mIdx=v>>4, NCH=16.
// BM=128, BK=64, BN=64 col-pairs. sB rows c: [gateLo|upLo|gateHi|upHi] x32.
__global__ __launch_bounds__(256) void gu_gemm(
    const unsigned short* __restrict__ xbf, const float* __restrict__ wgu,
    const float* __restrict__ sgu,
    unsigned short* __restrict__ act_r, unsigned short* __restrict__ act_s,
    const int* __restrict__ lists, const int* __restrict__ counts)
{
  __shared__ unsigned short sA[128 * 64];
  __shared__ unsigned short sB[128 * 64];
  __shared__ int sAid[128];

  const int tid = threadIdx.x;
  const int L = blockIdx.x;
  const bool routed = (L < 512);
  int e, mIdx, n0, count, NPAIR, NCH, LDB;
  const float* Bsrc;
  unsigned short* act;
  if (routed){
    e = L >> 5; int r = L & 31; mIdx = r >> 3; n0 = (r & 7) * 64;
    count = counts[e]; NPAIR = IR; NCH = 4; LDB = 2 * IR;
    Bsrc = wgu + (size_t)e * HDIM * (2 * IR);
    act = act_r;
  } else {
    int v = L - 512;
    e = 0; mIdx = v >> 4; n0 = (v & 15) * 64;
    count = NTOK; NPAIR = ISH; NCH = 16; LDB = 2 * ISH;
    Bsrc = sgu; act = act_s;
  }

  const int wv = tid >> 6, lane = tid & 63, lr = lane & 15, g = lane >> 4;
  const int wm = wv >> 1, wn = wv & 1;

  // B staging thread geometry: a = n-quad (0..31), o = k-octet (0..7)
  const int a = tid & 31, o = tid >> 5;
  const int alo = a & 15, aup = a >> 4;
  const int grp = ((alo >> 3) << 1) | aup;               // 0 gateLo,1 upLo,2 gateHi,3 upHi
  const int cbase = grp * 32 + 4 * (alo & 7);            // sB row base for this thread
  const int bsw = alo & 7;                               // (cbase>>2)&7 swizzle key
  const int gcol = n0 + 4 * alo + (aup ? NPAIR : 0);     // global col base (i=0)
  const float* bthread = Bsrc + (size_t)(o * 8) * LDB + gcol;

  for (int mt = mIdx; mt * 128 < count; mt += NCH){
    const int m0 = mt * 128;
    __syncthreads();
    if (tid < 128){
      int idx = m0 + tid;
      int aid;
      if (routed) aid = (idx < count) ? lists[e * NTOK + idx] : lists[e * NTOK];
      else        aid = idx;
      sAid[tid] = aid;
    }
    __syncthreads();
    const unsigned short* asrc[4];
    #pragma unroll
    for (int it = 0; it < 4; it++){
      int s = tid + it * 256;
      int row = s >> 3, ch = s & 7;
      int aid = sAid[row];
      int tok = routed ? (aid >> 2) : aid;
      asrc[it] = xbf + (size_t)tok * HDIM + ch * 8;
    }

    const f32x4 z4 = {0.f, 0.f, 0.f, 0.f};
    f32x4 acc[4][4];
    #pragma unroll
    for (int i = 0; i < 4; i++)
      #pragma unroll
      for (int j = 0; j < 4; j++) acc[i][j] = z4;

    for (int k0 = 0; k0 < HDIM; k0 += 64){
      // A: async global->LDS (bf16, linear)
      #pragma unroll
      for (int it = 0; it < 4; it++)
        gl_lds16(asrc[it] + k0, sA + (tid + it * 256) * 8);
      // B: 8 coalesced float4 rows -> convert -> transposed b128 LDS writes
      float4 f[8];
      const float* bp = bthread + (size_t)k0 * LDB;
      #pragma unroll
      for (int r = 0; r < 8; r++)
        f[r] = *(const float4*)(bp + (size_t)r * LDB);
      #pragma unroll
      for (int i = 0; i < 4; i++){
        const float* fp0 = (const float*)&f[0];
        bf16x8 pk = { (short)f2bf(((const float*)&f[0])[i]), (short)f2bf(((const float*)&f[1])[i]),
                      (short)f2bf(((const float*)&f[2])[i]), (short)f2bf(((const float*)&f[3])[i]),
                      (short)f2bf(((const float*)&f[4])[i]), (short)f2bf(((const float*)&f[5])[i]),
                      (short)f2bf(((const float*)&f[6])[i]), (short)f2bf(((const float*)&f[7])[i]) };
        (void)fp0;
        int c = cbase + i;
        *(bf16x8*)(sB + c * 64 + ((o ^ bsw) << 3)) = pk;
      }
      __syncthreads();
      #pragma unroll
      for (int h = 0; h < 2; h++){
        bf16x8 af[4], bfr[4];
        #pragma unroll
        for (int i = 0; i < 4; i++)
          af[i] = *(const bf16x8*)(sA + (wm * 64 + i * 16 + lr) * 64 + h * 32 + g * 8);
        #pragma unroll
        for (int i = 0; i < 4; i++){
          int c = wn * 64 + i * 16 + lr;
          int pos = (h * 4 + g) ^ ((c >> 2) & 7);
          bfr[i] = *(const bf16x8*)(sB + c * 64 + pos * 8);
        }
        #pragma unroll
        for (int mi = 0; mi < 4; mi++)
          #pragma unroll
          for (int ni = 0; ni < 4; ni++)
            acc[mi][ni] = __builtin_amdgcn_mfma_f32_16x16x32_bf16(af[mi], bfr[ni], acc[mi][ni], 0, 0, 0);
      }
      __syncthreads();
    }

    #pragma unroll
    for (int mi = 0; mi < 4; mi++){
      #pragma unroll
      for (int r = 0; r < 4; r++){
        int row = wm * 64 + mi * 16 + g * 4 + r;
        if (routed && m0 + row >= count) continue;
        int aid = sAid[row];
        size_t arow = (size_t)aid * NPAIR;
        #pragma unroll
        for (int ni = 0; ni < 2; ni++){
          float gv = acc[mi][ni][r];
          float uv = acc[mi][ni + 2][r];
          float av = gv / (1.f + __expf(-gv)) * uv;
          act[arow + n0 + wn * 32 + ni * 16 + lr] = f2bf(av);
        }
      }
    }
  }
}

// ---------------- fused down GEMM (fp32 B direct) ----------------
// Grid 640. L<512 routed: e=L>>5, r=L&31: p=r&7 -> n0=p*128, mIdx=r>>3, K=512, bf16->downout.
// L>=512 shared: v=L-512 (128): p=v&7 -> n0=p*128, mIdx=v>>3, K=1024, fp32->out.
__global__ __launch_bounds__(256) void down_gemm(
    const unsigned short* __restrict__ act_r, const unsigned short* __restrict__ act_s,
    const float* __restrict__ wdn, const float* __restrict__ sdn,
    float* __restrict__ out, unsigned short* __restrict__ downout,
    const int* __restrict__ lists, const int* __restrict__ counts)
{
  __shared__ unsigned short sA[128 * 64];
  __shared__ unsigned short sB[128 * 64];
  __shared__ int sAid[128];

  const int tid = threadIdx.x;
  const int L = blockIdx.x;
  const bool routed = (L < 512);
  int e, mIdx, n0, count, K, NCH;
  const float* Bsrc;
  const unsigned short* Ab;
  if (routed){
    e = L >> 5; int r = L & 31; mIdx = r >> 3; n0 = (r & 7) * 128;
    count = counts[e]; K = IR; NCH = 4;
    Bsrc = wdn + (size_t)e * IR * HDIM;
    Ab = act_r;
  } else {
    int v = L - 512;
    e = 0; mIdx = v >> 3; n0 = (v & 7) * 128;
    count = NTOK; K = ISH; NCH = 16;
    Bsrc = sdn; Ab = act_s;
  }

  const int wv = tid >> 6, lane = tid & 63, lr = lane & 15, g = lane >> 4;
  const int wm = wv >> 1, wn = wv & 1;

  const int a = tid & 31, o = tid >> 5;
  const int cbase = 4 * a;
  const int bsw = a & 7;
  const float* bthread = Bsrc + (size_t)(o * 8) * HDIM + n0 + 4 * a;

  for (int mt = mIdx; mt * 128 < count; mt += NCH){
    const int m0 = mt * 128;
    __syncthreads();
    if (tid < 128){
      int idx = m0 + tid;
      int aid;
      if (routed) aid = (idx < count) ? lists[e * NTOK + idx] : lists[e * NTOK];
      else        aid = idx;
      sAid[tid] = aid;
    }
    __syncthreads();
    const unsigned short* asrc[4];
    #pragma unroll
    for (int it = 0; it < 4; it++){
      int s = tid + it * 256;
      int row = s >> 3, ch = s & 7;
      asrc[it] = Ab + (size_t)sAid[row] * K + ch * 8;
    }

    const f32x4 z4 = {0.f, 0.f, 0.f, 0.f};
    f32x4 acc[4][4];
    #pragma unroll
    for (int i = 0; i < 4; i++)
      #pragma unroll
      for (int j = 0; j < 4; j++) acc[i][j] = z4;

    for (int k0 = 0; k0 < K; k0 += 64){
      #pragma unroll
      for (int it = 0; it < 4; it++)
        gl_lds16(asrc[it] + k0, sA + (tid + it * 256) * 8);
      float4 f[8];
      const float* bp = bthread + (size_t)k0 * HDIM;
      #pragma unroll
      for (int r = 0; r < 8; r++)
        f[r] = *(const float4*)(bp + (size_t)r * HDIM);
      #pragma unroll
      for (int i = 0; i < 4; i++){
        bf16x8 pk = { (short)f2bf(((const float*)&f[0])[i]), (short)f2bf(((const float*)&f[1])[i]),
                      (short)f2bf(((const float*)&f[2])[i]), (short)f2bf(((const float*)&f[3])[i]),
                      (short)f2bf(((const float*)&f[4])[i]), (short)f2bf(((const float*)&f[5])[i]),
                      (short)f2bf(((const float*)&f[6])[i]), (short)f2bf(((const float*)&f[7])[i]) };
        int c = cbase + i;
        *(bf16x8*)(sB + c * 64 + ((o ^ bsw) << 3)) = pk;
      }
      __syncthreads();
      #pragma unroll
      for (int h = 0; h < 2; h++){
        bf16x8 af[4], bfr[4];
        #pragma unroll
        for (int i = 0; i < 4; i++)
          af[i] = *(const bf16x8*)(sA + (wm * 64 + i * 16 + lr) * 64 + h * 32 + g * 8);
        #pragma unroll
        for (int i = 0; i < 4; i++){
          int c = wn * 64 + i * 16 + lr;
          int pos = (h * 4 + g) ^ ((c >> 2) & 7);
          bfr[i] = *(const bf16x8*)(sB + c * 64 + pos * 8);
        }
        #pragma unroll
        for (int mi = 0; mi < 4; mi++)
          #pragma unroll
          for (int ni = 0; ni < 4; ni++)
            acc[mi][ni] = __builtin_amdgcn_mfma_f32_16x16x32_bf16(af[mi], bfr[ni], acc[mi][ni], 0, 0, 0);
      }
      __syncthreads();
    }

    #pragma unroll
    for (int mi = 0; mi < 4; mi++){
      #pragma unroll
      for (int r = 0; r < 4; r++){
        int row = wm * 64 + mi * 16 + g * 4 + r;
        if (m0 + row >= count) continue;
        int aid = sAid[row];
        size_t orow = (size_t)aid * HDIM;
        if (routed){
          #pragma unroll
          for (int ni = 0; ni < 4; ni++)
            downout[orow + n0 + wn * 64 + ni * 16 + lr] = f2bf(acc[mi][ni][r]);
        } else {
          #pragma unroll
          for (int ni = 0; ni < 4; ni++)
            out[orow + n0 + wn * 64 + ni * 16 + lr] = acc[mi][ni][r];
        }
      }
    }
  }
}

// ---------------- combine: out += RSCALE * sum_k w_k * down_k ----------------
__global__ __launch_bounds__(256) void combine_kernel(
    float* __restrict__ out, const unsigned short* __restrict__ downout,
    const float* __restrict__ topkw)
{
  const int idx = blockIdx.x * 256 + threadIdx.x;
  const int t = idx >> 8;
  const int c4 = (idx & 255) * 4;
  float4 o = *(float4*)(out + (size_t)t * HDIM + c4);
  float r0 = 0.f, r1 = 0.f, r2 = 0.f, r3 = 0.f;
  #pragma unroll
  for (int k = 0; k < TOPK; k++){
    float w = topkw[t * TOPK + k];
    const ushort4 dv = *(const ushort4*)(downout + (size_t)(t * TOPK + k) * HDIM + c4);
    r0 += w * bf2f(dv.x); r1 += w * bf2f(dv.y);
    r2 += w * bf2f(dv.z); r3 += w * bf2f(dv.w);
  }
  o.x += RSCALE * r0; o.y += RSCALE * r1; o.z += RSCALE * r2; o.w += RSCALE * r3;
  *(float4*)(out + (size_t)t * HDIM + c4) = o;
}

extern "C" void kernel_launch(void* const* d_in, const int* in_sizes, int n_in,
                              void* d_out, int out_size, void* d_ws, size_t ws_size,
                              hipStream_t stream) {
  const float* x   = (const float*)d_in[0];
  const float* gw  = (const float*)d_in[1];
  const float* wgu = (const float*)d_in[2];
  const float* wdn = (const float*)d_in[3];
  const float* sgu = (const float*)d_in[4];
  const float* sdn = (const float*)d_in[5];
  float* out = (float*)d_out;

  char* ws = (char*)d_ws;
  float* topkw = (float*)(ws + 0);                                        // 32 KB
  int* choice  = (int*)(ws + 32768);                                      // 32 KB
  int* counts  = (int*)(ws + 65536);                                      // 256 B
  int* lists   = (int*)(ws + 65792);                                      // 128 KB -> 196864
  unsigned short* xbf     = (unsigned short*)(ws + 197120);               // 4 MB
  unsigned short* act_r   = (unsigned short*)(ws + 197120 +  4194304ull); // 8 MB
  unsigned short* act_s   = (unsigned short*)(ws + 197120 + 12582912ull); // 4 MB
  unsigned short* downout = (unsigned short*)(ws + 197120 + 16777216ull); // 16 MB -> ~33 MB total

  router_kernel<<<NTOK / 4, 256, 0, stream>>>(x, gw, topkw, choice, xbf);
  build_lists<<<NEXP, 256, 0, stream>>>(choice, counts, lists);
  gu_gemm<<<768, 256, 0, stream>>>(xbf, wgu, sgu, act_r, act_s, lists, counts);
  down_gemm<<<640, 256, 0, stream>>>(act_r, act_s, wdn, sdn, out, downout, lists, counts);
  combine_kernel<<<(NTOK * HDIM / 4) / 256, 256, 0, stream>>>(out, downout, topkw);
}

// Round 12
// 130.397 us; speedup vs baseline: 1.0854x; 1.0854x over previous
//
#include <hip/hip_runtime.h>
#include <hip/hip_bf16.h>
#include <stdint.h>

#define NTOK 2048
#define HDIM 1024
#define NEXP 16
#define TOPK 4
#define IR   512
#define ISH  1024
#define RSCALE 2.5f

typedef short bf16x4 __attribute__((ext_vector_type(4)));
typedef short bf16x8 __attribute__((ext_vector_type(8)));
typedef float f32x4  __attribute__((ext_vector_type(4)));

static __device__ __forceinline__ unsigned short f2bf(float f){
  union { float fv; uint32_t u; } v; v.fv = f;
  uint32_t r = v.u + 0x7fffu + ((v.u >> 16) & 1u);
  return (unsigned short)(r >> 16);
}
static __device__ __forceinline__ float bf2f(unsigned short s){
  union { uint32_t u; float f; } v; v.u = ((uint32_t)s) << 16;
  return v.f;
}
static __device__ __forceinline__ unsigned int pkbf2(float lo, float hi){
  union { __hip_bfloat162 b; unsigned int u; } cv;
  cv.b = __float22bfloat162_rn(make_float2(lo, hi));
  return cv.u;
}

// ---------------- router: logits, sigmoid, top-4, x->bf16 ----------------
__global__ __launch_bounds__(256) void router_kernel(
    const float* __restrict__ x, const float* __restrict__ gw,
    float* __restrict__ topkw, int* __restrict__ choice,
    unsigned short* __restrict__ xbf)
{
  __shared__ float sgw[NEXP][HDIM + 8];
  const int tid = threadIdx.x;
  for (int f = tid; f < HDIM * NEXP; f += 256){
    int i = f >> 4, e = f & 15;
    sgw[e][i] = gw[f];
  }
  __syncthreads();
  const int lane = tid & 63;
  const int t = blockIdx.x * 4 + (tid >> 6);

  float s[NEXP];
  #pragma unroll
  for (int e = 0; e < NEXP; e++) s[e] = 0.f;
  #pragma unroll
  for (int j = 0; j < 8; j++){
    const int off = 128 * j + lane * 2;
    float2 xv = *(const float2*)(x + (size_t)t * HDIM + off);
    ushort2 xs = { f2bf(xv.x), f2bf(xv.y) };
    *(ushort2*)(xbf + (size_t)t * HDIM + off) = xs;
    #pragma unroll
    for (int e = 0; e < NEXP; e++){
      float2 gv = *(const float2*)(&sgw[e][off]);
      s[e] += xv.x * gv.x + xv.y * gv.y;
    }
  }
  #pragma unroll
  for (int e = 0; e < NEXP; e++){
    #pragma unroll
    for (int off = 32; off; off >>= 1)
      s[e] += __shfl_xor(s[e], off);
  }
  float sc[NEXP];
  #pragma unroll
  for (int e = 0; e < NEXP; e++) sc[e] = 1.f / (1.f + __expf(-s[e]));

  unsigned mask = 0; float w[TOPK]; int id[TOPK];
  #pragma unroll
  for (int k = 0; k < TOPK; k++){
    float best = -1e30f; int bi = 0;
    #pragma unroll
    for (int e = 0; e < NEXP; e++){
      if (!((mask >> e) & 1u) && sc[e] > best){ best = sc[e]; bi = e; }
    }
    mask |= 1u << bi; id[k] = bi; w[k] = best;
  }
  float inv = 1.f / (w[0] + w[1] + w[2] + w[3]);
  if (lane == 0){
    #pragma unroll
    for (int k = 0; k < TOPK; k++){
      topkw[t * TOPK + k] = w[k] * inv;
      choice[t * TOPK + k] = id[k];
    }
  }
}

// ---------------- build per-expert lists deterministically ----------------
__global__ __launch_bounds__(256) void build_lists(
    const int* __restrict__ choice, int* __restrict__ counts, int* __restrict__ lists)
{
  const int e = blockIdx.x;
  const int tid = threadIdx.x;
  __shared__ int scnt[256];
  const int base = tid * 32;
  unsigned m = 0; int local = 0;
  #pragma unroll
  for (int i = 0; i < 32; i++){
    bool hit = (choice[base + i] == e);
    m |= (unsigned)hit << i;
    local += hit;
  }
  scnt[tid] = local;
  __syncthreads();
  int v = local;
  for (int off = 1; off < 256; off <<= 1){
    int add = (tid >= off) ? scnt[tid - off] : 0;
    __syncthreads();
    v += add; scnt[tid] = v;
    __syncthreads();
  }
  int pos = v - local;
  #pragma unroll
  for (int i = 0; i < 32; i++){
    if ((m >> i) & 1u) lists[e * NTOK + pos++] = base + i;
  }
  if (tid == 255) counts[e] = v;
}

// ---------------- fused gate_up GEMM (fp32 B direct, reg-staged A and B) ----------------
// Grid 768. L<512 routed: e=L>>5, r=L&31: n-panel p=r&7 (XCD-pinned), mIdx=r>>3, NCH=4.
// L>=512 shared: v=L-512: p=v&15, mIdx=v>>4, NCH=16.
// BM=128, BK=64, BN=64 col-pairs. sB rows c: [gateLo|upLo|gateHi|upHi] x32.
// LDS layout (both sA, sB): row*64 + (chunk ^ ((row>>1)&7))*8, chunk = k-octet.
__global__ __launch_bounds__(256) void gu_gemm(
    const unsigned short* __restrict__ xbf, const float* __restrict__ wgu,
    const float* __restrict__ sgu,
    unsigned short* __restrict__ act_r, unsigned short* __restrict__ act_s,
    const int* __restrict__ lists, const int* __restrict__ counts)
{
  __shared__ unsigned short sA[128 * 64];
  __shared__ unsigned short sB[128 * 64];
  __shared__ int sAid[128];

  const int tid = threadIdx.x;
  const int L = blockIdx.x;
  const bool routed = (L < 512);
  int e, mIdx, n0, count, NPAIR, NCH, LDB;
  const float* Bsrc;
  unsigned short* act;
  if (routed){
    e = L >> 5; int r = L & 31; mIdx = r >> 3; n0 = (r & 7) * 64;
    count = counts[e]; NPAIR = IR; NCH = 4; LDB = 2 * IR;
    Bsrc = wgu + (size_t)e * HDIM * (2 * IR);
    act = act_r;
  } else {
    int v = L - 512;
    e = 0; mIdx = v >> 4; n0 = (v & 15) * 64;
    count = NTOK; NPAIR = ISH; NCH = 16; LDB = 2 * ISH;
    Bsrc = sgu; act = act_s;
  }

  const int wv = tid >> 6, lane = tid & 63, lr = lane & 15, g = lane >> 4;
  const int wm = wv >> 1, wn = wv & 1;
  const int sw = lr >> 1;                                // read-side swizzle key

  // A staging geometry: thread handles 4 chunks; s = tid + it*256, row=s>>3, j=s&7.
  // LDS slot: row*64 + (j ^ ((row>>1)&7))*8  (16B ds_write, conflict-spread)
  // B staging thread geometry: a = n-quad (0..31), o = k-octet (0..7)
  const int a = tid & 31, o = tid >> 5;
  const int alo = a & 15, aup = a >> 4;
  const int grp = ((alo >> 3) << 1) | aup;               // 0 gateLo,1 upLo,2 gateHi,3 upHi
  const int cbase = grp * 32 + 4 * (alo & 7);            // sB row base for this thread
  const int gcol = n0 + 4 * alo + (aup ? NPAIR : 0);     // global col base (i=0)
  const float* bthread = Bsrc + (size_t)(o * 8) * LDB + gcol;

  for (int mt = mIdx; mt * 128 < count; mt += NCH){
    const int m0 = mt * 128;
    __syncthreads();
    if (tid < 128){
      int idx = m0 + tid;
      int aid;
      if (routed) aid = (idx < count) ? lists[e * NTOK + idx] : lists[e * NTOK];
      else        aid = idx;
      sAid[tid] = aid;
    }
    __syncthreads();
    const unsigned short* asrc[4];
    unsigned short* adst[4];
    #pragma unroll
    for (int it = 0; it < 4; it++){
      int s = tid + it * 256;
      int row = s >> 3, j = s & 7;
      int aid = sAid[row];
      int tok = routed ? (aid >> 2) : aid;
      asrc[it] = xbf + (size_t)tok * HDIM + j * 8;       // linear coalesced source
      adst[it] = sA + row * 64 + (j ^ ((row >> 1) & 7)) * 8;
    }

    const f32x4 z4 = {0.f, 0.f, 0.f, 0.f};
    f32x4 acc[4][4];
    #pragma unroll
    for (int i = 0; i < 4; i++)
      #pragma unroll
      for (int j = 0; j < 4; j++) acc[i][j] = z4;

    for (int k0 = 0; k0 < HDIM; k0 += 64){
      // A: reg-staged global -> swizzled LDS
      bf16x8 av[4];
      #pragma unroll
      for (int it = 0; it < 4; it++)
        av[it] = *(const bf16x8*)(asrc[it] + k0);
      #pragma unroll
      for (int it = 0; it < 4; it++)
        *(bf16x8*)adst[it] = av[it];
      // B: 8 coalesced float4 rows -> packed cvt -> swizzled transposed LDS
      float4 f[8];
      const float* bp = bthread + (size_t)k0 * LDB;
      #pragma unroll
      for (int r = 0; r < 8; r++)
        f[r] = *(const float4*)(bp + (size_t)r * LDB);
      #pragma unroll
      for (int i = 0; i < 4; i++){
        union { bf16x8 v; unsigned int u[4]; } pk;
        #pragma unroll
        for (int rp = 0; rp < 4; rp++){
          float lo = ((const float*)&f[2 * rp    ])[i];
          float hi = ((const float*)&f[2 * rp + 1])[i];
          pk.u[rp] = pkbf2(lo, hi);
        }
        int c = cbase + i;
        int pos = o ^ ((c >> 1) & 7);
        *(bf16x8*)(sB + c * 64 + pos * 8) = pk.v;
      }
      __syncthreads();
      #pragma unroll
      for (int h = 0; h < 2; h++){
        bf16x8 af[4], bfr[4];
        #pragma unroll
        for (int i = 0; i < 4; i++){
          int jx = ((h * 4 + g) ^ sw) * 8;
          af[i]  = *(const bf16x8*)(sA + (wm * 64 + i * 16 + lr) * 64 + jx);
          bfr[i] = *(const bf16x8*)(sB + (wn * 64 + i * 16 + lr) * 64 + jx);
        }
        #pragma unroll
        for (int mi = 0; mi < 4; mi++)
          #pragma unroll
          for (int ni = 0; ni < 4; ni++)
            acc[mi][ni] = __builtin_amdgcn_mfma_f32_16x16x32_bf16(af[mi], bfr[ni], acc[mi][ni], 0, 0, 0);
      }
      __syncthreads();
    }

    #pragma unroll
    for (int mi = 0; mi < 4; mi++){
      #pragma unroll
      for (int r = 0; r < 4; r++){
        int row = wm * 64 + mi * 16 + g * 4 + r;
        if (routed && m0 + row >= count) continue;
        int aid = sAid[row];
        size_t arow = (size_t)aid * NPAIR;
        #pragma unroll
        for (int ni = 0; ni < 2; ni++){
          float gv = acc[mi][ni][r];
          float uv = acc[mi][ni + 2][r];
          float av2 = gv / (1.f + __expf(-gv)) * uv;
          act[arow + n0 + wn * 32 + ni * 16 + lr] = f2bf(av2);
        }
      }
    }
  }
}

// ---------------- fused down GEMM (fp32 B direct, reg-staged) ----------------
// Grid 640. L<512 routed: e=L>>5, r=L&31: p=r&7 -> n0=p*128, mIdx=r>>3, K=512, bf16->downout.
// L>=512 shared: v=L-512 (128): p=v&7 -> n0=p*128, mIdx=v>>3, K=1024, fp32->shout.
__global__ __launch_bounds__(256) void down_gemm(
    const unsigned short* __restrict__ act_r, const unsigned short* __restrict__ act_s,
    const float* __restrict__ wdn, const float* __restrict__ sdn,
    float* __restrict__ shout, unsigned short* __restrict__ downout,
    const int* __restrict__ lists, const int* __restrict__ counts)
{
  __shared__ unsigned short sA[128 * 64];
  __shared__ unsigned short sB[128 * 64];
  __shared__ int sAid[128];

  const int tid = threadIdx.x;
  const int L = blockIdx.x;
  const bool routed = (L < 512);
  int e, mIdx, n0, count, K, NCH;
  const float* Bsrc;
  const unsigned short* Ab;
  if (routed){
    e = L >> 5; int r = L & 31; mIdx = r >> 3; n0 = (r & 7) * 128;
    count = counts[e]; K = IR; NCH = 4;
    Bsrc = wdn + (size_t)e * IR * HDIM;
    Ab = act_r;
  } else {
    int v = L - 512;
    e = 0; mIdx = v >> 3; n0 = (v & 7) * 128;
    count = NTOK; K = ISH; NCH = 16;
    Bsrc = sdn; Ab = act_s;
  }

  const int wv = tid >> 6, lane = tid & 63, lr = lane & 15, g = lane >> 4;
  const int wm = wv >> 1, wn = wv & 1;
  const int sw = lr >> 1;

  const int a = tid & 31, o = tid >> 5;
  const int cbase = 4 * a;
  const float* bthread = Bsrc + (size_t)(o * 8) * HDIM + n0 + 4 * a;

  for (int mt = mIdx; mt * 128 < count; mt += NCH){
    const int m0 = mt * 128;
    __syncthreads();
    if (tid < 128){
      int idx = m0 + tid;
      int aid;
      if (routed) aid = (idx < count) ? lists[e * NTOK + idx] : lists[e * NTOK];
      else        aid = idx;
      sAid[tid] = aid;
    }
    __syncthreads();
    const unsigned short* asrc[4];
    unsigned short* adst[4];
    #pragma unroll
    for (int it = 0; it < 4; it++){
      int s = tid + it * 256;
      int row = s >> 3, j = s & 7;
      asrc[it] = Ab + (size_t)sAid[row] * K + j * 8;
      adst[it] = sA + row * 64 + (j ^ ((row >> 1) & 7)) * 8;
    }

    const f32x4 z4 = {0.f, 0.f, 0.f, 0.f};
    f32x4 acc[4][4];
    #pragma unroll
    for (int i = 0; i < 4; i++)
      #pragma unroll
      for (int j = 0; j < 4; j++) acc[i][j] = z4;

    for (int k0 = 0; k0 < K; k0 += 64){
      bf16x8 av[4];
      #pragma unroll
      for (int it = 0; it < 4; it++)
        av[it] = *(const bf16x8*)(asrc[it] + k0);
      #pragma unroll
      for (int it = 0; it < 4; it++)
        *(bf16x8*)adst[it] = av[it];
      float4 f[8];
      const float* bp = bthread + (size_t)k0 * HDIM;
      #pragma unroll
      for (int r = 0; r < 8; r++)
        f[r] = *(const float4*)(bp + (size_t)r * HDIM);
      #pragma unroll
      for (int i = 0; i < 4; i++){
        union { bf16x8 v; unsigned int u[4]; } pk;
        #pragma unroll
        for (int rp = 0; rp < 4; rp++){
          float lo = ((const float*)&f[2 * rp    ])[i];
          float hi = ((const float*)&f[2 * rp + 1])[i];
          pk.u[rp] = pkbf2(lo, hi);
        }
        int c = cbase + i;
        int pos = o ^ ((c >> 1) & 7);
        *(bf16x8*)(sB + c * 64 + pos * 8) = pk.v;
      }
      __syncthreads();
      #pragma unroll
      for (int h = 0; h < 2; h++){
        bf16x8 af[4], bfr[4];
        #pragma unroll
        for (int i = 0; i < 4; i++){
          int jx = ((h * 4 + g) ^ sw) * 8;
          af[i]  = *(const bf16x8*)(sA + (wm * 64 + i * 16 + lr) * 64 + jx);
          bfr[i] = *(const bf16x8*)(sB + (wn * 64 + i * 16 + lr) * 64 + jx);
        }
        #pragma unroll
        for (int mi = 0; mi < 4; mi++)
          #pragma unroll
          for (int ni = 0; ni < 4; ni++)
            acc[mi][ni] = __builtin_amdgcn_mfma_f32_16x16x32_bf16(af[mi], bfr[ni], acc[mi][ni], 0, 0, 0);
      }
      __syncthreads();
    }

    #pragma unroll
    for (int mi = 0; mi < 4; mi++){
      #pragma unroll
      for (int r = 0; r < 4; r++){
        int row = wm * 64 + mi * 16 + g * 4 + r;
        if (m0 + row >= count) continue;
        int aid = sAid[row];
        size_t orow = (size_t)aid * HDIM;
        if (routed){
          #pragma unroll
          for (int ni = 0; ni < 4; ni++)
            downout[orow + n0 + wn * 64 + ni * 16 + lr] = f2bf(acc[mi][ni][r]);
        } else {
          #pragma unroll
          for (int ni = 0; ni < 4; ni++)
            shout[orow + n0 + wn * 64 + ni * 16 + lr] = acc[mi][ni][r];
        }
      }
    }
  }
}

// ---------------- combine (pure store): out = shout + RSCALE * sum_k w_k * down_k ----------------
__global__ __launch_bounds__(256) void combine_kernel(
    float* __restrict__ out, const float* __restrict__ shout,
    const unsigned short* __restrict__ downout, const float* __restrict__ topkw)
{
  const int idx = blockIdx.x * 256 + threadIdx.x;
  const int t = idx >> 8;
  const int c4 = (idx & 255) * 4;
  float4 o = *(const float4*)(shout + (size_t)t * HDIM + c4);
  float r0 = 0.f, r1 = 0.f, r2 = 0.f, r3 = 0.f;
  #pragma unroll
  for (int k = 0; k < TOPK; k++){
    float w = topkw[t * TOPK + k];
    const ushort4 dv = *(const ushort4*)(downout + (size_t)(t * TOPK + k) * HDIM + c4);
    r0 += w * bf2f(dv.x); r1 += w * bf2f(dv.y);
    r2 += w * bf2f(dv.z); r3 += w * bf2f(dv.w);
  }
  o.x += RSCALE * r0; o.y += RSCALE * r1; o.z += RSCALE * r2; o.w += RSCALE * r3;
  *(float4*)(out + (size_t)t * HDIM + c4) = o;
}

extern "C" void kernel_launch(void* const* d_in, const int* in_sizes, int n_in,
                              void* d_out, int out_size, void* d_ws, size_t ws_size,
                              hipStream_t stream) {
  const float* x   = (const float*)d_in[0];
  const float* gw  = (const float*)d_in[1];
  const float* wgu = (const float*)d_in[2];
  const float* wdn = (const float*)d_in[3];
  const float* sgu = (const float*)d_in[4];
  const float* sdn = (const float*)d_in[5];
  float* out = (float*)d_out;

  char* ws = (char*)d_ws;
  float* topkw = (float*)(ws + 0);                                        // 32 KB
  int* choice  = (int*)(ws + 32768);                                      // 32 KB
  int* counts  = (int*)(ws + 65536);                                      // 256 B
  int* lists   = (int*)(ws + 65792);                                      // 128 KB -> 196864
  unsigned short* xbf     = (unsigned short*)(ws + 197120);               // 4 MB
  unsigned short* act_r   = (unsigned short*)(ws + 197120 +  4194304ull); // 8 MB
  unsigned short* act_s   = (unsigned short*)(ws + 197120 + 12582912ull); // 4 MB
  unsigned short* downout = (unsigned short*)(ws + 197120 + 16777216ull); // 16 MB
  float*          shout   = (float*)(ws + 197120 + 33554432ull);          // 8 MB -> ~41.8 MB total

  router_kernel<<<NTOK / 4, 256, 0, stream>>>(x, gw, topkw, choice, xbf);
  build_lists<<<NEXP, 256, 0, stream>>>(choice, counts, lists);
  gu_gemm<<<768, 256, 0, stream>>>(xbf, wgu, sgu, act_r, act_s, lists, counts);
  down_gemm<<<640, 256, 0, stream>>>(act_r, act_s, wdn, sdn, shout, downout, lists, counts);
  combine_kernel<<<(NTOK * HDIM / 4) / 256, 256, 0, stream>>>(out, shout, downout, topkw);
}